// Round 5
// baseline (813.420 us; speedup 1.0000x reference)
//
#include <hip/hip_runtime.h>
#include <hip/hip_fp16.h>
#include <stdint.h>

#define NEG_ (-1e9f)
#define TILES 4   // m-tiles per block; grid = 2048/TILES = 512 (2 blocks/CU)

typedef _Float16 f16x8 __attribute__((ext_vector_type(8)));
typedef float    f32x4 __attribute__((ext_vector_type(4)));

__device__ __forceinline__ float fast_tanh(float x) {
  float e = __expf(2.0f * x);
  return (e - 1.0f) * __builtin_amdgcn_rcpf(e + 1.0f);
}

// Raw workgroup barrier with LDS visibility ONLY (lgkmcnt(0)).
// Does NOT drain vmcnt: __syncthreads lowering emits s_waitcnt vmcnt(0)
// before s_barrier, which would kill the cross-tile X prefetch. Register
// deps on the in-flight loads are waited at first use (the convert).
__device__ __forceinline__ void bar_lds() {
  asm volatile("s_waitcnt lgkmcnt(0)" ::: "memory");
  __builtin_amdgcn_s_barrier();
  __builtin_amdgcn_sched_barrier(0);
}

// ---------------------------------------------------------------------------
// K0: repack W [512 o][512 h] fp32 -> f16 in MFMA A-fragment stream order.
// seg = w*64 + ks*4 + io  (1KB each); w in 0..7 is the owning wave.
// lane i holds W[o = w*64+io*16+(i&15)][k = ks*32+(i>>4)*8 .. +8)
// ---------------------------------------------------------------------------
__global__ __launch_bounds__(256) void k0_cvt_w(const float* __restrict__ W,
                                                __half* __restrict__ Wws) {
  int g = blockIdx.x * 256 + threadIdx.x;   // 0..32767, one 16B chunk each
  int lane = g & 63;
  int seg  = g >> 6;                        // 0..511
  int io = seg & 3, ks = (seg >> 2) & 15, w = seg >> 6;   // w: 0..7
  int o = w * 64 + io * 16 + (lane & 15);
  int k = ks * 32 + (lane >> 4) * 8;
  const float2* src = (const float2*)(W + (size_t)o * 512 + k);
  __half2 h[4];
#pragma unroll
  for (int j = 0; j < 4; ++j) { float2 f = src[j]; h[j] = __floats2half2_rn(f.x, f.y); }
  uint4 u;
  u.x = *(uint32_t*)&h[0]; u.y = *(uint32_t*)&h[1];
  u.z = *(uint32_t*)&h[2]; u.w = *(uint32_t*)&h[3];
  *(uint4*)(Wws + (size_t)seg * 512 + (size_t)lane * 8) = u;
}

// ---------------------------------------------------------------------------
// K1 (fused + tile-pipelined, register-disciplined): each block owns TILES
// consecutive 64-row chunks. Round-3 structure per tile; the next tile's 16
// float4 X loads are issued at the ONE point where acc (64 AGPR) and abuf
// (48 VGPR) are both dead -- immediately after the tanh fold -- so the
// combined live set stays within the 128-reg/4-waves-per-SIMD budget
// (round 4 issued them while acc was live: 192 regs -> scratch spill,
// 1.08 GB HBM traffic). In-order vmcnt: xr issued after the tile's last
// A-load, drained by xconv before the next tile's first A-wait.
// ---------------------------------------------------------------------------
__global__ __launch_bounds__(512, 4) void k1_scores(
    const float* __restrict__ enc, const int* __restrict__ msk,
    const float* __restrict__ bias, const float* __restrict__ ctx,
    const __half* __restrict__ Wws, float* __restrict__ scores,
    float* __restrict__ psum, float* __restrict__ mpart,
    float* __restrict__ lpart) {
  __shared__ __align__(16) __half Xl[64 * 512];  // 64 KB
  __shared__ float sred[512];
  __shared__ float pbuf[64];

  const int t = threadIdx.x;
  const int w = t >> 6;          // 0..7: wave / o-chunk
  const int lane = t & 63;
  const int quad = lane >> 4;
  const int l15 = lane & 15;
  const size_t m0 = (size_t)blockIdx.x * TILES;

  // ---- A-fragment register ring (depth-2) from L2-resident Wws ----
  f16x8 abuf[3][4];
  auto aload = [&](int slot, int ks) {
    const f16x8* sp = (const f16x8*)(Wws +
        ((size_t)(w * 64 + ks * 4) * 512) + (size_t)lane * 8);
#pragma unroll
    for (int io = 0; io < 4; ++io) abuf[slot][io] = sp[io * 64];
  };

  // ---- X staging (chunk j -> s = 8j + w, c = lane) ----
  float4 xr[16];     // in-flight fp32 payload of the NEXT tile (64 VGPR)
  auto xissue = [&](size_t mt) {
    const float4* Xg = (const float4*)(enc + mt * (size_t)(64 * 512));
#pragma unroll
    for (int j = 0; j < 8; ++j) {
      int s = 8 * j + w;
      xr[2 * j]     = Xg[s * 128 + 2 * lane];
      xr[2 * j + 1] = Xg[s * 128 + 2 * lane + 1];
    }
  };
  auto xstore = [&]() {            // fused convert + swizzled LDS write
#pragma unroll
    for (int j = 0; j < 8; ++j) {
      int s = 8 * j + w;
      float4 x0 = xr[2 * j], x1 = xr[2 * j + 1];
      __half2 h0 = __floats2half2_rn(x0.x, x0.y);
      __half2 h1 = __floats2half2_rn(x0.z, x0.w);
      __half2 h2 = __floats2half2_rn(x1.x, x1.y);
      __half2 h3 = __floats2half2_rn(x1.z, x1.w);
      uint4 u;
      u.x = *(uint32_t*)&h0; u.y = *(uint32_t*)&h1;
      u.z = *(uint32_t*)&h2; u.w = *(uint32_t*)&h3;
      int pc = lane ^ (s & 7);     // XOR swizzle: conflict-free b128 both ways
      *(uint4*)&Xl[s * 512 + pc * 8] = u;
    }
  };

  // ---- prologue: stage tile m0 ----
  xissue(m0);
  xstore();
  bar_lds();

#pragma unroll 1
  for (int i = 0; i < TILES; ++i) {
    const size_t mtile = m0 + i;

    aload(0, 0);
    aload(1, 1);

    f32x4 acc[4][4];
#pragma unroll
    for (int io = 0; io < 4; ++io)
#pragma unroll
      for (int is = 0; is < 4; ++is) acc[io][is] = (f32x4){0.f, 0.f, 0.f, 0.f};

#pragma unroll
    for (int ks = 0; ks < 16; ++ks) {
      if (ks + 2 < 16) aload((ks + 2) % 3, ks + 2);  // prefetch ahead
      const f16x8* acur = abuf[ks % 3];
#pragma unroll
      for (int is = 0; is < 4; ++is) {
        int s = is * 16 + l15;
        const f16x8 bf = *(const f16x8*)&Xl[s * 512 + (((ks * 4 + quad) ^ (s & 7)) << 3)];
#pragma unroll
        for (int io = 0; io < 4; ++io)
          acc[io][is] = __builtin_amdgcn_mfma_f32_16x16x32_f16(acur[io], bf, acc[io][is], 0, 0, 0);
      }
    }

    // epilogue: fold tanh(acc + b) * v into per-row partial scores.
    // acc dies HERE -- this is the register window for the X prefetch.
    float ps[4] = {0.f, 0.f, 0.f, 0.f};
#pragma unroll
    for (int io = 0; io < 4; ++io) {
      int ob = w * 64 + io * 16 + quad * 4;  // C row m = quad*4 + reg
      float4 b4 = *(const float4*)(bias + ob);
      float4 v4 = *(const float4*)(ctx + ob);
#pragma unroll
      for (int is = 0; is < 4; ++is) {
        const f32x4 a = acc[io][is];
        ps[is] += fast_tanh(a[0] + b4.x) * v4.x + fast_tanh(a[1] + b4.y) * v4.y +
                  fast_tanh(a[2] + b4.z) * v4.z + fast_tanh(a[3] + b4.w) * v4.w;
      }
    }

    // issue next tile's X loads: acc/abuf dead, after all A-issues of this
    // tile (in-order vmcnt). sched_barrier keeps them from hoisting into
    // the region where acc was live.
    __builtin_amdgcn_sched_barrier(0);
    if (i + 1 < TILES) xissue(mtile + 1);
    __builtin_amdgcn_sched_barrier(0);

#pragma unroll
    for (int is = 0; is < 4; ++is) {   // sum over this wave's 64 o's
      ps[is] += __shfl_xor(ps[is], 16, 64);
      ps[is] += __shfl_xor(ps[is], 32, 64);
    }

    bar_lds();
    if (lane < 16) {
#pragma unroll
      for (int is = 0; is < 4; ++is) sred[w * 64 + is * 16 + lane] = ps[is];
    }
    bar_lds();
    if (t < 64) {   // wave 0: finalize scores + local softmax stats
      float sc = 0.f;
#pragma unroll
      for (int k = 0; k < 8; ++k) sc += sred[k * 64 + t];
      size_t row = mtile * 64 + t;
      float sm = msk[row] ? sc : NEG_;
      scores[row] = sm;                     // raw masked score for combine
      float m = sm;
#pragma unroll
      for (int off = 32; off >= 1; off >>= 1) m = fmaxf(m, __shfl_xor(m, off, 64));
      float p = __expf(sm - m);
      float l = p;
#pragma unroll
      for (int off = 32; off >= 1; off >>= 1) l += __shfl_xor(l, off, 64);
      pbuf[t] = p;
      if (t == 0) { mpart[mtile] = m; lpart[mtile] = l; }
    }
    bar_lds();

    // partial weighted sum from the resident LDS X tile:
    // wave w covers s = w*8..w*8+7; lane c covers h = c*8..c*8+7
    float pacc[8] = {0.f, 0.f, 0.f, 0.f, 0.f, 0.f, 0.f, 0.f};
    const int c = lane;
#pragma unroll
    for (int si = 0; si < 8; ++si) {
      int s = (w << 3) + si;
      float pv = pbuf[s];
      f16x8 xv = *(const f16x8*)&Xl[s * 512 + ((c ^ (s & 7)) << 3)];
#pragma unroll
      for (int j = 0; j < 8; ++j) pacc[j] = fmaf(pv, (float)xv[j], pacc[j]);
    }
    bar_lds();                      // all psum reads of Xl done -> reuse as pred
    float* pred = (float*)&Xl[0];   // layout [w][half][c][4] (first 16 KB)
    {
      float4 lo = {pacc[0], pacc[1], pacc[2], pacc[3]};
      float4 hi = {pacc[4], pacc[5], pacc[6], pacc[7]};
      *(float4*)&pred[w * 512 + c * 4] = lo;
      *(float4*)&pred[w * 512 + 256 + c * 4] = hi;
    }
    bar_lds();
    if (t < 128) {                  // h float4-group = t
      int half = t & 1, c2 = t >> 1;
      float4 a = {0.f, 0.f, 0.f, 0.f};
#pragma unroll
      for (int w2 = 0; w2 < 8; ++w2) {
        float4 pv = *(const float4*)&pred[w2 * 512 + half * 256 + c2 * 4];
        a.x += pv.x; a.y += pv.y; a.z += pv.z; a.w += pv.w;
      }
      *(float4*)&psum[mtile * 512 + (size_t)t * 4] = a;
    }
    bar_lds();                      // pred (Xl alias) reads done -> Xl dead

    if (i + 1 < TILES) xstore();    // vmcnt waits land here, mostly covered
    bar_lds();                      // staged tile visible for next MFMA phase
  }
}

// ---------------------------------------------------------------------------
// K2 (combine): per batch b, reduce 32 chunk partials:
//   M = max m_c; Z = sum l_c e^(m_c-M)
//   attn[b,s] = e^(score - M)/Z  (exact softmax, in place)
//   out[b,h]  = sum_c e^(m_c-M) * psum_c[h] / Z
// ---------------------------------------------------------------------------
__global__ __launch_bounds__(256) void k2_combine(
    float* __restrict__ attn, const float* __restrict__ psum,
    const float* __restrict__ mpart, const float* __restrict__ lpart,
    float* __restrict__ out0) {
  const int b = blockIdx.x, t = threadIdx.x;
  __shared__ float ml[32], ll[32];
  if (t < 32) { ml[t] = mpart[b * 32 + t]; ll[t] = lpart[b * 32 + t]; }
  __syncthreads();
  float M = -3.4e38f;
#pragma unroll
  for (int i = 0; i < 32; ++i) M = fmaxf(M, ml[i]);
  float wgt[32];
  float Z = 0.f;
#pragma unroll
  for (int i = 0; i < 32; ++i) {
    float e = __expf(ml[i] - M);
    wgt[i] = e;
    Z += e * ll[i];
  }
  float invZ = 1.0f / Z;
  float* row = attn + (size_t)b * 2048;
#pragma unroll
  for (int i = 0; i < 8; ++i) {
    int s = t + 256 * i;
    row[s] = __expf(row[s] - M) * invZ;
  }
  if (t < 128) {
    float4 a = {0.f, 0.f, 0.f, 0.f};
#pragma unroll
    for (int c2 = 0; c2 < 32; ++c2) {
      float wv = wgt[c2];
      float4 p = *(const float4*)&psum[((size_t)(b * 32 + c2)) * 512 + (size_t)t * 4];
      a.x = fmaf(wv, p.x, a.x);
      a.y = fmaf(wv, p.y, a.y);
      a.z = fmaf(wv, p.z, a.z);
      a.w = fmaf(wv, p.w, a.w);
    }
    float4 r = {a.x * invZ, a.y * invZ, a.z * invZ, a.w * invZ};
    *(float4*)&out0[(size_t)b * 512 + (size_t)t * 4] = r;
  }
}

// ---------------------------------------------------------------------------
extern "C" void kernel_launch(void* const* d_in, const int* in_sizes, int n_in,
                              void* d_out, int out_size, void* d_ws, size_t ws_size,
                              hipStream_t stream) {
  (void)in_sizes; (void)n_in; (void)out_size; (void)ws_size;
  const float* enc  = (const float*)d_in[0];  // [64,2048,512] fp32
  const int*   msk  = (const int*)d_in[1];    // [64,2048] bool->int32
  const float* W    = (const float*)d_in[2];  // [512,512] fp32
  const float* bias = (const float*)d_in[3];  // [512] fp32
  const float* ctx  = (const float*)d_in[4];  // [512] fp32
  float* out0 = (float*)d_out;                // [64,512] weighted output
  float* attn = out0 + 64 * 512;              // [64,2048] scores -> attn (in place)

  __half* Wws  = (__half*)d_ws;                               // 512 KB
  float*  psum = (float*)((char*)d_ws + (512u << 10));        // 4 MB  [2048][512]
  float*  mprt = psum + (size_t)2048 * 512;                   // 8 KB
  float*  lprt = mprt + 2048;                                 // 8 KB

  k0_cvt_w<<<128, 256, 0, stream>>>(W, Wws);
  k1_scores<<<2048 / TILES, 512, 0, stream>>>(enc, msk, bias, ctx, Wws, attn,
                                              psum, mprt, lprt);
  k2_combine<<<64, 256, 0, stream>>>(attn, psum, mprt, lprt, out0);
}

// Round 6
// 591.373 us; speedup vs baseline: 1.3755x; 1.3755x over previous
//
#include <hip/hip_runtime.h>
#include <hip/hip_fp16.h>
#include <stdint.h>

#define NEG_ (-1e9f)
#define TILES 8   // m-tiles per block; grid = 2048/TILES = 256 (1 block/CU)

typedef _Float16 f16x8 __attribute__((ext_vector_type(8)));
typedef float    f32x4 __attribute__((ext_vector_type(4)));

__device__ __forceinline__ float fast_tanh(float x) {
  float e = __expf(2.0f * x);
  return (e - 1.0f) * __builtin_amdgcn_rcpf(e + 1.0f);
}

// Raw workgroup barrier with LDS visibility ONLY (lgkmcnt(0)).
// Does NOT drain vmcnt: __syncthreads lowering emits s_waitcnt vmcnt(0)
// before s_barrier, which would kill the cross-tile X prefetch. Register
// deps on the in-flight loads are waited at first use (the convert).
__device__ __forceinline__ void bar_lds() {
  asm volatile("s_waitcnt lgkmcnt(0)" ::: "memory");
  __builtin_amdgcn_s_barrier();
  __builtin_amdgcn_sched_barrier(0);
}

// ---------------------------------------------------------------------------
// K0: repack W [512 o][512 h] fp32 -> f16 in MFMA A-fragment stream order.
// seg = w*64 + ks*4 + io  (1KB each); w in 0..7 is the owning wave.
// lane i holds W[o = w*64+io*16+(i&15)][k = ks*32+(i>>4)*8 .. +8)
// ---------------------------------------------------------------------------
__global__ __launch_bounds__(256) void k0_cvt_w(const float* __restrict__ W,
                                                __half* __restrict__ Wws) {
  int g = blockIdx.x * 256 + threadIdx.x;   // 0..32767, one 16B chunk each
  int lane = g & 63;
  int seg  = g >> 6;                        // 0..511
  int io = seg & 3, ks = (seg >> 2) & 15, w = seg >> 6;   // w: 0..7
  int o = w * 64 + io * 16 + (lane & 15);
  int k = ks * 32 + (lane >> 4) * 8;
  const float2* src = (const float2*)(W + (size_t)o * 512 + k);
  __half2 h[4];
#pragma unroll
  for (int j = 0; j < 4; ++j) { float2 f = src[j]; h[j] = __floats2half2_rn(f.x, f.y); }
  uint4 u;
  u.x = *(uint32_t*)&h[0]; u.y = *(uint32_t*)&h[1];
  u.z = *(uint32_t*)&h[2]; u.w = *(uint32_t*)&h[3];
  *(uint4*)(Wws + (size_t)seg * 512 + (size_t)lane * 8) = u;
}

// ---------------------------------------------------------------------------
// K1 (fused, tile-pipelined, NO-SPILL budget): 512 thr, 1 block/CU
// (LDS ~150 KB), __launch_bounds__(512,2) -> 256 combined regs/thread so
// abuf(48) + acc(64 AGPR) + xr(64) all stay in registers (rounds 2-5 spilled
// xr to scratch under the 128-reg/4-wave budget: up to 1.3 GB HBM spill
// traffic). Double-buffered X tile: MFMA reads Xl[cur] while the next
// tile's 16 float4 loads fly through the epilogue and land in Xl[cur^1].
// xissue is placed AFTER the tile's last A-ring load (vmcnt retires in
// order); xstore drains xr before the next tile issues A-loads.
// ---------------------------------------------------------------------------
__global__ __launch_bounds__(512, 2) void k1_scores(
    const float* __restrict__ enc, const int* __restrict__ msk,
    const float* __restrict__ bias, const float* __restrict__ ctx,
    const __half* __restrict__ Wws, float* __restrict__ scores,
    float* __restrict__ psum, float* __restrict__ mpart,
    float* __restrict__ lpart) {
  __shared__ __align__(16) __half Xl[2][64 * 512];  // 128 KB double buffer
  __shared__ float sred[512];
  __shared__ float pbuf[64];
  __shared__ __align__(16) float pred[8 * 512];     // 16 KB (no Xl aliasing)

  const int t = threadIdx.x;
  const int w = t >> 6;          // 0..7: wave / o-chunk
  const int lane = t & 63;
  const int quad = lane >> 4;
  const int l15 = lane & 15;
  const size_t m0 = (size_t)blockIdx.x * TILES;

  // ---- A-fragment register ring (depth-2) from L2-resident Wws ----
  f16x8 abuf[3][4];
  auto aload = [&](int slot, int ks) {
    const f16x8* sp = (const f16x8*)(Wws +
        ((size_t)(w * 64 + ks * 4) * 512) + (size_t)lane * 8);
#pragma unroll
    for (int io = 0; io < 4; ++io) abuf[slot][io] = sp[io * 64];
  };

  // ---- X staging (chunk j -> s = 8j + w, c = lane) ----
  float4 xr[16];     // in-flight fp32 payload of the NEXT tile (64 VGPR)
  auto xissue = [&](size_t mt) {
    const float4* Xg = (const float4*)(enc + mt * (size_t)(64 * 512));
#pragma unroll
    for (int j = 0; j < 8; ++j) {
      int s = 8 * j + w;
      xr[2 * j]     = Xg[s * 128 + 2 * lane];
      xr[2 * j + 1] = Xg[s * 128 + 2 * lane + 1];
    }
  };
  auto xstore = [&](int buf) {     // fused convert + swizzled LDS write
#pragma unroll
    for (int j = 0; j < 8; ++j) {
      int s = 8 * j + w;
      float4 x0 = xr[2 * j], x1 = xr[2 * j + 1];
      __half2 h0 = __floats2half2_rn(x0.x, x0.y);
      __half2 h1 = __floats2half2_rn(x0.z, x0.w);
      __half2 h2 = __floats2half2_rn(x1.x, x1.y);
      __half2 h3 = __floats2half2_rn(x1.z, x1.w);
      uint4 u;
      u.x = *(uint32_t*)&h0; u.y = *(uint32_t*)&h1;
      u.z = *(uint32_t*)&h2; u.w = *(uint32_t*)&h3;
      int pc = lane ^ (s & 7);     // XOR swizzle: conflict-free b128 both ways
      *(uint4*)&Xl[buf][s * 512 + pc * 8] = u;
    }
  };

  // ---- prologue: stage tile m0 into buffer 0 ----
  xissue(m0);
  xstore(0);
  bar_lds();

#pragma unroll 1
  for (int i = 0; i < TILES; ++i) {
    const size_t mtile = m0 + i;
    const int cur = i & 1;

    aload(0, 0);
    aload(1, 1);

    f32x4 acc[4][4];
#pragma unroll
    for (int io = 0; io < 4; ++io)
#pragma unroll
      for (int is = 0; is < 4; ++is) acc[io][is] = (f32x4){0.f, 0.f, 0.f, 0.f};

#pragma unroll
    for (int ks = 0; ks < 16; ++ks) {
      if (ks + 2 < 16) aload((ks + 2) % 3, ks + 2);  // prefetch ahead
      const f16x8* acur = abuf[ks % 3];
#pragma unroll
      for (int is = 0; is < 4; ++is) {
        int s = is * 16 + l15;
        const f16x8 bf =
            *(const f16x8*)&Xl[cur][s * 512 + (((ks * 4 + quad) ^ (s & 7)) << 3)];
#pragma unroll
        for (int io = 0; io < 4; ++io)
          acc[io][is] = __builtin_amdgcn_mfma_f32_16x16x32_f16(acur[io], bf, acc[io][is], 0, 0, 0);
      }
    }

    // issue next tile's X loads: after ALL A-issues of this tile (in-order
    // vmcnt retirement). The transfer flies through the whole epilogue.
    __builtin_amdgcn_sched_barrier(0);
    if (i + 1 < TILES) xissue(mtile + 1);
    __builtin_amdgcn_sched_barrier(0);

    // epilogue: fold tanh(acc + b) * v into per-row partial scores
    float ps[4] = {0.f, 0.f, 0.f, 0.f};
#pragma unroll
    for (int io = 0; io < 4; ++io) {
      int ob = w * 64 + io * 16 + quad * 4;  // C row m = quad*4 + reg
      float4 b4 = *(const float4*)(bias + ob);
      float4 v4 = *(const float4*)(ctx + ob);
#pragma unroll
      for (int is = 0; is < 4; ++is) {
        const f32x4 a = acc[io][is];
        ps[is] += fast_tanh(a[0] + b4.x) * v4.x + fast_tanh(a[1] + b4.y) * v4.y +
                  fast_tanh(a[2] + b4.z) * v4.z + fast_tanh(a[3] + b4.w) * v4.w;
      }
    }
#pragma unroll
    for (int is = 0; is < 4; ++is) {   // sum over this wave's 64 o's
      ps[is] += __shfl_xor(ps[is], 16, 64);
      ps[is] += __shfl_xor(ps[is], 32, 64);
    }

    bar_lds();
    if (lane < 16) {
#pragma unroll
      for (int is = 0; is < 4; ++is) sred[w * 64 + is * 16 + lane] = ps[is];
    }
    bar_lds();
    if (t < 64) {   // wave 0: finalize scores + local softmax stats
      float sc = 0.f;
#pragma unroll
      for (int k = 0; k < 8; ++k) sc += sred[k * 64 + t];
      size_t row = mtile * 64 + t;
      float sm = msk[row] ? sc : NEG_;
      scores[row] = sm;                     // raw masked score for combine
      float m = sm;
#pragma unroll
      for (int off = 32; off >= 1; off >>= 1) m = fmaxf(m, __shfl_xor(m, off, 64));
      float p = __expf(sm - m);
      float l = p;
#pragma unroll
      for (int off = 32; off >= 1; off >>= 1) l += __shfl_xor(l, off, 64);
      pbuf[t] = p;
      if (t == 0) { mpart[mtile] = m; lpart[mtile] = l; }
    }
    bar_lds();

    // partial weighted sum from the resident LDS X tile:
    // wave w covers s = w*8..w*8+7; lane c covers h = c*8..c*8+7
    float pacc[8] = {0.f, 0.f, 0.f, 0.f, 0.f, 0.f, 0.f, 0.f};
    const int c = lane;
#pragma unroll
    for (int si = 0; si < 8; ++si) {
      int s = (w << 3) + si;
      float pv = pbuf[s];
      f16x8 xv = *(const f16x8*)&Xl[cur][s * 512 + ((c ^ (s & 7)) << 3)];
#pragma unroll
      for (int j = 0; j < 8; ++j) pacc[j] = fmaf(pv, (float)xv[j], pacc[j]);
    }
    // pred is a dedicated buffer (no Xl aliasing) -> write immediately
    {
      float4 lo = {pacc[0], pacc[1], pacc[2], pacc[3]};
      float4 hi = {pacc[4], pacc[5], pacc[6], pacc[7]};
      *(float4*)&pred[w * 512 + c * 4] = lo;
      *(float4*)&pred[w * 512 + 256 + c * 4] = hi;
    }
    bar_lds();
    if (t < 128) {                  // h float4-group = t
      int half = t & 1, c2 = t >> 1;
      float4 a = {0.f, 0.f, 0.f, 0.f};
#pragma unroll
      for (int w2 = 0; w2 < 8; ++w2) {
        float4 pv = *(const float4*)&pred[w2 * 512 + half * 256 + c2 * 4];
        a.x += pv.x; a.y += pv.y; a.z += pv.z; a.w += pv.w;
      }
      *(float4*)&psum[mtile * 512 + (size_t)t * 4] = a;
    }

    // land the next tile into the other buffer; vmcnt register deps drain
    // here, covered by the epilogue above.
    if (i + 1 < TILES) xstore(cur ^ 1);
    bar_lds();                      // staged tile visible for next MFMA phase
  }
}

// ---------------------------------------------------------------------------
// K2 (combine): per batch b, reduce 32 chunk partials:
//   M = max m_c; Z = sum l_c e^(m_c-M)
//   attn[b,s] = e^(score - M)/Z  (exact softmax, in place)
//   out[b,h]  = sum_c e^(m_c-M) * psum_c[h] / Z
// ---------------------------------------------------------------------------
__global__ __launch_bounds__(256) void k2_combine(
    float* __restrict__ attn, const float* __restrict__ psum,
    const float* __restrict__ mpart, const float* __restrict__ lpart,
    float* __restrict__ out0) {
  const int b = blockIdx.x, t = threadIdx.x;
  __shared__ float ml[32], ll[32];
  if (t < 32) { ml[t] = mpart[b * 32 + t]; ll[t] = lpart[b * 32 + t]; }
  __syncthreads();
  float M = -3.4e38f;
#pragma unroll
  for (int i = 0; i < 32; ++i) M = fmaxf(M, ml[i]);
  float wgt[32];
  float Z = 0.f;
#pragma unroll
  for (int i = 0; i < 32; ++i) {
    float e = __expf(ml[i] - M);
    wgt[i] = e;
    Z += e * ll[i];
  }
  float invZ = 1.0f / Z;
  float* row = attn + (size_t)b * 2048;
#pragma unroll
  for (int i = 0; i < 8; ++i) {
    int s = t + 256 * i;
    row[s] = __expf(row[s] - M) * invZ;
  }
  if (t < 128) {
    float4 a = {0.f, 0.f, 0.f, 0.f};
#pragma unroll
    for (int c2 = 0; c2 < 32; ++c2) {
      float wv = wgt[c2];
      float4 p = *(const float4*)&psum[((size_t)(b * 32 + c2)) * 512 + (size_t)t * 4];
      a.x = fmaf(wv, p.x, a.x);
      a.y = fmaf(wv, p.y, a.y);
      a.z = fmaf(wv, p.z, a.z);
      a.w = fmaf(wv, p.w, a.w);
    }
    float4 r = {a.x * invZ, a.y * invZ, a.z * invZ, a.w * invZ};
    *(float4*)&out0[(size_t)b * 512 + (size_t)t * 4] = r;
  }
}

// ---------------------------------------------------------------------------
extern "C" void kernel_launch(void* const* d_in, const int* in_sizes, int n_in,
                              void* d_out, int out_size, void* d_ws, size_t ws_size,
                              hipStream_t stream) {
  (void)in_sizes; (void)n_in; (void)out_size; (void)ws_size;
  const float* enc  = (const float*)d_in[0];  // [64,2048,512] fp32
  const int*   msk  = (const int*)d_in[1];    // [64,2048] bool->int32
  const float* W    = (const float*)d_in[2];  // [512,512] fp32
  const float* bias = (const float*)d_in[3];  // [512] fp32
  const float* ctx  = (const float*)d_in[4];  // [512] fp32
  float* out0 = (float*)d_out;                // [64,512] weighted output
  float* attn = out0 + 64 * 512;              // [64,2048] scores -> attn (in place)

  __half* Wws  = (__half*)d_ws;                               // 512 KB
  float*  psum = (float*)((char*)d_ws + (512u << 10));        // 4 MB  [2048][512]
  float*  mprt = psum + (size_t)2048 * 512;                   // 8 KB
  float*  lprt = mprt + 2048;                                 // 8 KB

  k0_cvt_w<<<128, 256, 0, stream>>>(W, Wws);
  k1_scores<<<2048 / TILES, 512, 0, stream>>>(enc, msk, bias, ctx, Wws, attn,
                                              psum, mprt, lprt);
  k2_combine<<<64, 256, 0, stream>>>(attn, psum, mprt, lprt, out0);
}